// Round 10
// baseline (251.372 us; speedup 1.0000x reference)
//
#include <hip/hip_runtime.h>

// Problem: B=4, S=2048, D=1024, H=16, W=64.
// Inputs fp32, output fp32; compute in bf16 MFMA.
#define B_ 4
#define S_ 2048
#define D_ 1024
#define H_ 16
#define W_ 64

typedef __attribute__((ext_vector_type(8))) __bf16 bf16x8;
typedef __attribute__((ext_vector_type(4))) __bf16 bf16x4;
typedef __attribute__((ext_vector_type(4))) float f32x4;

static __device__ __forceinline__ void gload_lds16(const void* g, void* l) {
  __builtin_amdgcn_global_load_lds((const __attribute__((address_space(1))) void*)g,
                                   (__attribute__((address_space(3))) void*)l,
                                   16, 0, 0);
}

#define MFMA16(a, b, c) __builtin_amdgcn_mfma_f32_16x16x32_bf16((a), (b), (c), 0, 0, 0)

// Raw v_exp_f32 (2^x). exp2f libcall carries non-fast-math range checks (R6 lesson).
#if __has_builtin(__builtin_amdgcn_exp2f)
#define EXP2(x) __builtin_amdgcn_exp2f(x)
#else
#define EXP2(x) __expf((x) * 0.6931472f)
#endif

// ---------------------------------------------------------------------------
// Kernel 1: convert x (fp32) -> bf16 scratch. 8 elems/thread.
// (R9's merged prep reverted: it cost ~+6us vs separate launches.)
// ---------------------------------------------------------------------------
__global__ __launch_bounds__(256) void convx(const float* __restrict__ x,
                                             __bf16* __restrict__ xb) {
  const size_t i = ((size_t)blockIdx.x * 256 + threadIdx.x) * 8;
  const f32x4 v0 = *(const f32x4*)(x + i);
  const f32x4 v1 = *(const f32x4*)(x + i + 4);
  bf16x8 v;
#pragma unroll
  for (int k = 0; k < 4; k++) { v[k] = (__bf16)v0[k]; v[4 + k] = (__bf16)v1[k]; }
  *(bf16x8*)(xb + i) = v;
}

// ---------------------------------------------------------------------------
// Kernel 2: weight transpose+convert W[k][n] (fp32) -> T[n][k] bf16
// ---------------------------------------------------------------------------
__global__ __launch_bounds__(256) void wtrans(
    const float* __restrict__ Wq, const float* __restrict__ Wk, const float* __restrict__ Wv,
    __bf16* __restrict__ Tq, __bf16* __restrict__ Tk, __bf16* __restrict__ Tv) {
  __shared__ __bf16 t[64][65];
  const int z = blockIdx.z;
  const float* W = (z == 0) ? Wq : (z == 1) ? Wk : Wv;
  __bf16* T = (z == 0) ? Tq : (z == 1) ? Tk : Tv;
  const int n0 = blockIdx.x * 64, k0 = blockIdx.y * 64;
  const int row = threadIdx.x >> 2, c0 = (threadIdx.x & 3) * 16;
#pragma unroll
  for (int i = 0; i < 16; i++)
    t[row][c0 + i] = (__bf16)W[(size_t)(k0 + row) * D_ + n0 + c0 + i];
  __syncthreads();
#pragma unroll
  for (int i = 0; i < 16; i++) T[(size_t)(n0 + row) * D_ + k0 + c0 + i] = t[c0 + i][row];
}

// ---------------------------------------------------------------------------
// Kernel 3: bias convert fp32 -> bf16 in ws (3 x 1024)
// ---------------------------------------------------------------------------
__global__ __launch_bounds__(256) void convb(
    const float* __restrict__ bq, const float* __restrict__ bk, const float* __restrict__ bv,
    __bf16* __restrict__ dst) {
  const int z = blockIdx.x;
  const float* src = (z == 0) ? bq : (z == 1) ? bk : bv;
  const int i = threadIdx.x * 4;
#pragma unroll
  for (int k = 0; k < 4; k++) dst[z * 1024 + i + k] = (__bf16)src[i + k];
}

// ---------------------------------------------------------------------------
// Kernel 4: fused QKV projection GEMM. BK=64, m97-structure K-loop. Bijective
//   XCD chunk swizzle (R1: proven).
//   R10: SWAPPED-OPERAND MFMA — MFMA16(bb[j], a[i], .) computes the same
//   products with row(quad*4+r)->n, col->m (fragment formats are symmetric:
//   result row follows arg0's free index, cf. attn's PV usage). The 4 r-values
//   are then w-contiguous for Q/K's [B,H,S,64] layout -> bf16x4 stores (16
//   vector stores/thread instead of 64 scalar); V falls back to 4 scalar
//   stores. Net: 2 of 3 outputs vectorized instead of 1 of 3. Bit-identical
//   arithmetic (same products, same accumulation tree).
//   Q scaled by 0.125*log2(e); Q,K written [B,H,S,64]; V written [B,H,64,S].
// ---------------------------------------------------------------------------
__global__ __launch_bounds__(256) void qkv_gemm(
    const __bf16* __restrict__ x,
    const __bf16* __restrict__ Tq, const __bf16* __restrict__ Tk, const __bf16* __restrict__ Tv,
    const __bf16* __restrict__ biasb,
    __bf16* __restrict__ Qo, __bf16* __restrict__ Ko, __bf16* __restrict__ Vto) {
  __shared__ __align__(16) __bf16 As[128 * 64];  // [row][k], 128B rows, chunk-swizzled
  __shared__ __align__(16) __bf16 Bs[128 * 64];
  const int tid = threadIdx.x, lane = tid & 63;
  const int wid = tid >> 6, wm = wid >> 1, wn = wid & 1;
  const int quad = lane >> 4, col = lane & 15;
  const int sw = col & 7;
  // XCD chunk swizzle: 1536 blocks = 8 XCDs x 192. XCD k gets contiguous nids
  // [192k,192k+192): 24 consecutive (m,z)-panels x all 8 n-blocks.
  const int id = blockIdx.x + (blockIdx.y << 3) + (blockIdx.z << 9);
  const int nid = (id & 7) * 192 + (id >> 3);
  const int n0 = (nid & 7) * 128, m0 = ((nid >> 3) & 63) * 128, z = nid >> 9;
  const __bf16* Wt = (z == 0) ? Tq : (z == 1) ? Tk : Tv;
  const __bf16* bias = biasb + z * 1024;

  f32x4 acc[4][4] = {};

  // staging: thread's 16B chunk c=tid&7 of row r=(tid>>3)+32j; source chunk
  // swizzled c^(r&7) -> constant per-thread offset soff.
  const int srow = tid >> 3;
  const int soff = (((tid & 7) ^ ((tid >> 3) & 7)) << 4);

  for (int kt = 0; kt < D_ / 64; ++kt) {
    const int k0 = kt * 64;
    __syncthreads();
    const char* ax = (const char*)x + (size_t)(m0 + srow) * (D_ * 2) + k0 * 2 + soff;
    const char* bx = (const char*)Wt + (size_t)(n0 + srow) * (D_ * 2) + k0 * 2 + soff;
#pragma unroll
    for (int j = 0; j < 4; j++) {
      gload_lds16(ax + (size_t)j * 32 * (D_ * 2), (char*)As + tid * 16 + j * 4096);
      gload_lds16(bx + (size_t)j * 32 * (D_ * 2), (char*)Bs + tid * 16 + j * 4096);
    }
    __syncthreads();

#pragma unroll
    for (int kk = 0; kk < 2; kk++) {
      const int pc = (((kk << 2) + quad) ^ sw) << 3;  // physical chunk offset (elems)
      bf16x8 a[4], bb[4];
#pragma unroll
      for (int i = 0; i < 4; i++)
        a[i] = *(const bf16x8*)(As + (wm * 64 + 16 * i + col) * 64 + pc);
#pragma unroll
      for (int j = 0; j < 4; j++)
        bb[j] = *(const bf16x8*)(Bs + (wn * 64 + 16 * j + col) * 64 + pc);
#pragma unroll
      for (int i = 0; i < 4; i++)
#pragma unroll
        for (int j = 0; j < 4; j++) acc[i][j] = MFMA16(bb[j], a[i], acc[i][j]);
    }
  }

  // epilogue (swapped-operand form): lane holds D[n = quad*4+r within 16j]
  // [m = col within 16i]. Q/K: r-values w-contiguous -> bf16x4 store; V: s
  // fixed per lane -> 4 scalar stores at stride S.
  const float scale = (z == 0) ? 0.18033688f : 1.0f;  // 0.125 * log2(e) for Q
#pragma unroll
  for (int j = 0; j < 4; j++) {
    const int nb = n0 + wn * 64 + 16 * j + quad * 4;  // n for r=0; r spans +0..3
    const int h = nb >> 6, wq = nb & 63;              // same h for all 4 r
    const bf16x4 bv = *(const bf16x4*)(bias + nb);
#pragma unroll
    for (int i = 0; i < 4; i++) {
      const int m = m0 + wm * 64 + 16 * i + col;
      const int b = m >> 11, s = m & 2047;
      if (z < 2) {
        bf16x4 v;
#pragma unroll
        for (int r = 0; r < 4; r++) v[r] = (__bf16)((acc[i][j][r] + (float)bv[r]) * scale);
        *(bf16x4*)(((z == 0) ? Qo : Ko) + ((size_t)(b * H_ + h) * S_ + s) * W_ + wq) = v;
      } else {
#pragma unroll
        for (int r = 0; r < 4; r++)
          Vto[((size_t)(b * H_ + h) * W_ + wq + r) * S_ + s] =
              (__bf16)(acc[i][j][r] + (float)bv[r]);
      }
    }
  }
}

// ---------------------------------------------------------------------------
// Kernel 5: flash attention. Byte-identical to R7's passing version (S^T
//   formulation, XOR-swizzled K/V LDS, double-buffer + prefetch across the
//   single per-tile barrier, in-register P via cvt_pk+permlane, VALU l-sum).
//   R6/R8 restructures (mt-split, ones-MFMA l-sum) both failed correctness
//   for undiagnosed reasons — this inner loop is frozen.
// ---------------------------------------------------------------------------
__global__ __launch_bounds__(256, 4) void attn(
    const __bf16* __restrict__ Q, const __bf16* __restrict__ K,
    const __bf16* __restrict__ Vt, const int* __restrict__ mask,
    float* __restrict__ out) {
  __shared__ __align__(16) __bf16 Kl[2][64 * 64];  // [buf][key][w], chunk-swizzled
  __shared__ __align__(16) __bf16 Vl[2][64 * 64];  // [buf][w][key], chunk-swizzled
  __shared__ int Mfl[32];                          // per-tile: 1 = mask all ones

  const int tid = threadIdx.x, lane = tid & 63, wid = tid >> 6;
  const int quad = lane >> 4, col = lane & 15;
  // XCD chunk swizzle: 1024 blocks = 8 XCDs x 128. XCD k gets bh in [8k,8k+8),
  // qx fastest -> one head's 512KB K/V hot in its L2 at a time.
  const int id = blockIdx.x + (blockIdx.y << 4);
  const int nid = (id & 7) * 128 + (id >> 3);
  const int bh = nid >> 4, b = bh >> 4, h = bh & 15;
  const int qbase = (nid & 15) * 128 + wid * 32;
  const int sw = col & 7;

  // prologue: per-tile all-ones flags (wave w handles tiles w, w+4, ...)
  for (int kt2 = wid; kt2 < 32; kt2 += 4) {
    const int m = mask[b * S_ + kt2 * 64 + lane];
    const unsigned long long bal = __ballot(m != 0);
    if (lane == 0) Mfl[kt2] = (~bal == 0ull) ? 1 : 0;
  }

  // Q B-fragments (lane n=col holds Q[q][k=quad*8+j], kk chunks): qf[qg][kk]
  bf16x8 qf[2][2];
#pragma unroll
  for (int qg = 0; qg < 2; qg++) {
    const __bf16* qp = Q + ((size_t)bh * S_ + qbase + qg * 16 + col) * W_ + quad * 8;
    qf[qg][0] = *(const bf16x8*)qp;
    qf[qg][1] = *(const bf16x8*)(qp + 32);
  }

  f32x4 oacc[2][4] = {};
  float lrow[2] = {0.f, 0.f};

  // staging lanes: flat f -> row r (128B), chunk c; fetch global chunk c^(r&7)
  const int f1 = tid * 16, r1 = f1 >> 7, c1 = (f1 >> 4) & 7;
  const int f2 = f1 + 4096, r2 = f2 >> 7, c2 = (f2 >> 4) & 7;
  const int s1 = (c1 ^ (r1 & 7)) << 4, s2 = (c2 ^ (r2 & 7)) << 4;

#define STAGE_KV(kts, bufidx)                                                     \
  do {                                                                            \
    const int k0s = (kts) * 64;                                                   \
    const char* kg = (const char*)(K + ((size_t)bh * S_ + k0s) * W_);             \
    gload_lds16(kg + (size_t)r1 * 128 + s1, (char*)Kl[bufidx] + f1);              \
    gload_lds16(kg + (size_t)r2 * 128 + s2, (char*)Kl[bufidx] + f2);              \
    const char* vg = (const char*)(Vt + (size_t)bh * W_ * S_ + k0s);              \
    gload_lds16(vg + (size_t)r1 * (S_ * 2) + s1, (char*)Vl[bufidx] + f1);         \
    gload_lds16(vg + (size_t)r2 * (S_ * 2) + s2, (char*)Vl[bufidx] + f2);         \
  } while (0)

  // prologue stage of tile 0 into buffer 0
  STAGE_KV(0, 0);

  for (int kt = 0; kt < S_ / 64; ++kt) {
    const int cur = kt & 1;
    // single per-tile barrier: auto vmcnt drain covers tile-kt loads (issued a
    // full compute phase ago) + makes buf[cur^1] safe to overwrite.
    __syncthreads();
    if (kt + 1 < S_ / 64) STAGE_KV(kt + 1, cur ^ 1);

    const int allone = __builtin_amdgcn_readfirstlane(Mfl[kt]);
    const __bf16* Klc = Kl[cur];
    const __bf16* Vlc = Vl[cur];

    // St = K.Q^T : A-frag = K rows (m=key=16mt+col), B-frag = qf
    f32x4 sacc[2][4] = {};
    __builtin_amdgcn_s_setprio(1);
#pragma unroll
    for (int mt = 0; mt < 4; mt++) {
      const __bf16* kr = Klc + (16 * mt + col) * 64;
      const bf16x8 ka0 = *(const bf16x8*)(kr + ((quad ^ sw) << 3));
      const bf16x8 ka1 = *(const bf16x8*)(kr + (((4 + quad) ^ sw) << 3));
#pragma unroll
      for (int qg = 0; qg < 2; qg++) {
        sacc[qg][mt] = MFMA16(ka0, qf[qg][0], sacc[qg][mt]);
        sacc[qg][mt] = MFMA16(ka1, qf[qg][1], sacc[qg][mt]);
      }
    }
    __builtin_amdgcn_s_setprio(0);

    // additive mask slow path (wave-uniform branch; never taken for all-ones)
    if (!allone) {
      const int k0 = kt * 64;
#pragma unroll
      for (int mt = 0; mt < 4; mt++)
#pragma unroll
        for (int r = 0; r < 4; r++) {
          const int m = mask[b * S_ + k0 + 16 * mt + 4 * quad + r];
          const float madd = -14426.95f * (1.0f - (float)m);  // -10000*log2e
          sacc[0][mt][r] += madd;
          sacc[1][mt][r] += madd;
        }
    }

    // softmax partial: p = exp2(s') via raw v_exp_f32; vector l-sum;
    // pack P rows to dwords in-register (keys 4q+{0,1} in pkA, {2,3} in pkB)
    unsigned pkA[2][4], pkB[2][4];
#pragma unroll
    for (int qg = 0; qg < 2; qg++) {
      f32x4 vsum = {0.f, 0.f, 0.f, 0.f};
#pragma unroll
      for (int mt = 0; mt < 4; mt++) {
#pragma unroll
        for (int r = 0; r < 4; r++) sacc[qg][mt][r] = EXP2(sacc[qg][mt][r]);
        vsum += sacc[qg][mt];
      }
      float sum = (vsum[0] + vsum[1]) + (vsum[2] + vsum[3]);
      sum += __shfl_xor(sum, 16, 64);
      sum += __shfl_xor(sum, 32, 64);
      lrow[qg] += sum;
#pragma unroll
      for (int mt = 0; mt < 4; mt++) {
        __asm__("v_cvt_pk_bf16_f32 %0, %1, %2"
                : "=v"(pkA[qg][mt]) : "v"(sacc[qg][mt][0]), "v"(sacc[qg][mt][1]));
        __asm__("v_cvt_pk_bf16_f32 %0, %1, %2"
                : "=v"(pkB[qg][mt]) : "v"(sacc[qg][mt][2]), "v"(sacc[qg][mt][3]));
      }
    }

    // O^T += V^T.P^T : A-frag = V^T rows (m=w=16mt+col); B-frag built in-reg
    // via permlane32_swap + permlane16_swap (col fixed, quad permuted).
    __builtin_amdgcn_s_setprio(1);
#pragma unroll
    for (int kk = 0; kk < 2; kk++) {
      bf16x8 pf[2];
#pragma unroll
      for (int qg = 0; qg < 2; qg++) {
        unsigned a0 = pkA[qg][2 * kk], a1 = pkA[qg][2 * kk + 1];
        unsigned b0 = pkB[qg][2 * kk], b1 = pkB[qg][2 * kk + 1];
        __asm__("v_permlane32_swap_b32 %0, %1" : "+v"(a0), "+v"(a1));
        __asm__("v_permlane16_swap_b32 %0, %1" : "+v"(a0), "+v"(a1));
        __asm__("v_permlane32_swap_b32 %0, %1" : "+v"(b0), "+v"(b1));
        __asm__("v_permlane16_swap_b32 %0, %1" : "+v"(b0), "+v"(b1));
        // a0 = keys 8q+{0,1}, b0 = {2,3}, a1 = {4,5}, b1 = {6,7}
        union { unsigned u[4]; bf16x8 v; } pk_;
        pk_.u[0] = a0; pk_.u[1] = b0; pk_.u[2] = a1; pk_.u[3] = b1;
        pf[qg] = pk_.v;
      }
      const int vsw = ((kk * 4 + quad) ^ sw) << 3;
#pragma unroll
      for (int mt = 0; mt < 4; mt++) {
        const bf16x8 va = *(const bf16x8*)(Vlc + (16 * mt + col) * 64 + vsw);
        oacc[0][mt] = MFMA16(va, pf[0], oacc[0][mt]);
        oacc[1][mt] = MFMA16(va, pf[1], oacc[1][mt]);
      }
    }
    __builtin_amdgcn_s_setprio(0);
  }
#undef STAGE_KV

  // epilogue: lane holds O^T[w=16mt+quad*4+r][q=qg*16+col] -> fp32 dwordx4
#pragma unroll
  for (int qg = 0; qg < 2; qg++) {
    const float inv = 1.0f / lrow[qg];
    const int s = qbase + qg * 16 + col;
#pragma unroll
    for (int mt = 0; mt < 4; mt++) {
      f32x4 o;
#pragma unroll
      for (int r = 0; r < 4; r++) o[r] = oacc[qg][mt][r] * inv;
      *(f32x4*)(out + ((size_t)b * S_ + s) * D_ + h * 64 + 16 * mt + quad * 4) = o;
    }
  }
}

// ---------------------------------------------------------------------------
extern "C" void kernel_launch(void* const* d_in, const int* in_sizes, int n_in,
                              void* d_out, int out_size, void* d_ws, size_t ws_size,
                              hipStream_t stream) {
  const float* x  = (const float*)d_in[0];
  const int* mask = (const int*)d_in[1];
  const float* Wq = (const float*)d_in[2];
  const float* bq = (const float*)d_in[3];
  const float* Wk = (const float*)d_in[4];
  const float* bk = (const float*)d_in[5];
  const float* Wv = (const float*)d_in[6];
  const float* bv = (const float*)d_in[7];
  float* out = (float*)d_out;

  // d_out first half doubles as x-bf16 scratch; overwritten by attn at the end.
  __bf16* xb = (__bf16*)d_out;

  // ws: Q 16MB | K 16MB | V^T 16MB | Tq/Tk/Tv 3x2MB | bias 6KB
  char* ws = (char*)d_ws;
  __bf16* Qw  = (__bf16*)(ws);
  __bf16* Kw  = (__bf16*)(ws + 16777216);
  __bf16* Vtw = (__bf16*)(ws + 2 * 16777216);
  __bf16* Tq  = (__bf16*)(ws + 3 * 16777216);
  __bf16* Tk  = Tq + 1024 * 1024;
  __bf16* Tv  = Tk + 1024 * 1024;
  __bf16* biasb = Tv + 1024 * 1024;

  convx<<<4096, 256, 0, stream>>>(x, xb);
  wtrans<<<dim3(16, 16, 3), 256, 0, stream>>>(Wq, Wk, Wv, Tq, Tk, Tv);
  convb<<<3, 256, 0, stream>>>(bq, bk, bv, biasb);
  qkv_gemm<<<dim3(8, 64, 3), 256, 0, stream>>>(xb, Tq, Tk, Tv, biasb, Qw, Kw, Vtw);
  attn<<<dim3(16, 64), 256, 0, stream>>>(Qw, Kw, Vtw, mask, out);
}

// Round 11
// 243.058 us; speedup vs baseline: 1.0342x; 1.0342x over previous
//
#include <hip/hip_runtime.h>

// Problem: B=4, S=2048, D=1024, H=16, W=64.
// Inputs fp32, output fp32; compute in bf16 MFMA.
#define B_ 4
#define S_ 2048
#define D_ 1024
#define H_ 16
#define W_ 64

typedef __attribute__((ext_vector_type(8))) __bf16 bf16x8;
typedef __attribute__((ext_vector_type(4))) __bf16 bf16x4;
typedef __attribute__((ext_vector_type(4))) float f32x4;

static __device__ __forceinline__ void gload_lds16(const void* g, void* l) {
  __builtin_amdgcn_global_load_lds((const __attribute__((address_space(1))) void*)g,
                                   (__attribute__((address_space(3))) void*)l,
                                   16, 0, 0);
}

#define MFMA16(a, b, c) __builtin_amdgcn_mfma_f32_16x16x32_bf16((a), (b), (c), 0, 0, 0)

// Raw v_exp_f32 (2^x). exp2f libcall carries non-fast-math range checks (R6 lesson).
#if __has_builtin(__builtin_amdgcn_exp2f)
#define EXP2(x) __builtin_amdgcn_exp2f(x)
#else
#define EXP2(x) __expf((x) * 0.6931472f)
#endif

// ---------------------------------------------------------------------------
// Kernel 1: convert x (fp32) -> bf16 scratch. 8 elems/thread.
// ---------------------------------------------------------------------------
__global__ __launch_bounds__(256) void convx(const float* __restrict__ x,
                                             __bf16* __restrict__ xb) {
  const size_t i = ((size_t)blockIdx.x * 256 + threadIdx.x) * 8;
  const f32x4 v0 = *(const f32x4*)(x + i);
  const f32x4 v1 = *(const f32x4*)(x + i + 4);
  bf16x8 v;
#pragma unroll
  for (int k = 0; k < 4; k++) { v[k] = (__bf16)v0[k]; v[4 + k] = (__bf16)v1[k]; }
  *(bf16x8*)(xb + i) = v;
}

// ---------------------------------------------------------------------------
// Kernel 2: weight transpose+convert W[k][n] (fp32) -> T[n][k] bf16
// ---------------------------------------------------------------------------
__global__ __launch_bounds__(256) void wtrans(
    const float* __restrict__ Wq, const float* __restrict__ Wk, const float* __restrict__ Wv,
    __bf16* __restrict__ Tq, __bf16* __restrict__ Tk, __bf16* __restrict__ Tv) {
  __shared__ __bf16 t[64][65];
  const int z = blockIdx.z;
  const float* W = (z == 0) ? Wq : (z == 1) ? Wk : Wv;
  __bf16* T = (z == 0) ? Tq : (z == 1) ? Tk : Tv;
  const int n0 = blockIdx.x * 64, k0 = blockIdx.y * 64;
  const int row = threadIdx.x >> 2, c0 = (threadIdx.x & 3) * 16;
#pragma unroll
  for (int i = 0; i < 16; i++)
    t[row][c0 + i] = (__bf16)W[(size_t)(k0 + row) * D_ + n0 + c0 + i];
  __syncthreads();
#pragma unroll
  for (int i = 0; i < 16; i++) T[(size_t)(n0 + row) * D_ + k0 + c0 + i] = t[c0 + i][row];
}

// ---------------------------------------------------------------------------
// Kernel 3: bias convert fp32 -> bf16 in ws (3 x 1024)
// ---------------------------------------------------------------------------
__global__ __launch_bounds__(256) void convb(
    const float* __restrict__ bq, const float* __restrict__ bk, const float* __restrict__ bv,
    __bf16* __restrict__ dst) {
  const int z = blockIdx.x;
  const float* src = (z == 0) ? bq : (z == 1) ? bk : bv;
  const int i = threadIdx.x * 4;
#pragma unroll
  for (int k = 0; k < 4; k++) dst[z * 1024 + i + k] = (__bf16)src[i + k];
}

// ---------------------------------------------------------------------------
// Kernel 4: fused QKV projection GEMM. BK=64, m97-structure K-loop. Bijective
//   XCD chunk swizzle (R1: proven, FETCH_SIZE way down). R10's swapped-operand
//   epilogue reverted (+10us: fewer stores but worse coalescing).
//   Q scaled by 0.125*log2(e); Q,K written [B,H,S,64]; V written [B,H,64,S].
// ---------------------------------------------------------------------------
__global__ __launch_bounds__(256) void qkv_gemm(
    const __bf16* __restrict__ x,
    const __bf16* __restrict__ Tq, const __bf16* __restrict__ Tk, const __bf16* __restrict__ Tv,
    const __bf16* __restrict__ biasb,
    __bf16* __restrict__ Qo, __bf16* __restrict__ Ko, __bf16* __restrict__ Vto) {
  __shared__ __align__(16) __bf16 As[128 * 64];  // [row][k], 128B rows, chunk-swizzled
  __shared__ __align__(16) __bf16 Bs[128 * 64];
  const int tid = threadIdx.x, lane = tid & 63;
  const int wid = tid >> 6, wm = wid >> 1, wn = wid & 1;
  const int quad = lane >> 4, col = lane & 15;
  const int sw = col & 7;
  // XCD chunk swizzle: 1536 blocks = 8 XCDs x 192. XCD k gets contiguous nids
  // [192k,192k+192): 24 consecutive (m,z)-panels x all 8 n-blocks.
  const int id = blockIdx.x + (blockIdx.y << 3) + (blockIdx.z << 9);
  const int nid = (id & 7) * 192 + (id >> 3);
  const int n0 = (nid & 7) * 128, m0 = ((nid >> 3) & 63) * 128, z = nid >> 9;
  const __bf16* Wt = (z == 0) ? Tq : (z == 1) ? Tk : Tv;
  const __bf16* bias = biasb + z * 1024;

  f32x4 acc[4][4] = {};

  // staging: thread's 16B chunk c=tid&7 of row r=(tid>>3)+32j; source chunk
  // swizzled c^(r&7) -> constant per-thread offset soff.
  const int srow = tid >> 3;
  const int soff = (((tid & 7) ^ ((tid >> 3) & 7)) << 4);

  for (int kt = 0; kt < D_ / 64; ++kt) {
    const int k0 = kt * 64;
    __syncthreads();
    const char* ax = (const char*)x + (size_t)(m0 + srow) * (D_ * 2) + k0 * 2 + soff;
    const char* bx = (const char*)Wt + (size_t)(n0 + srow) * (D_ * 2) + k0 * 2 + soff;
#pragma unroll
    for (int j = 0; j < 4; j++) {
      gload_lds16(ax + (size_t)j * 32 * (D_ * 2), (char*)As + tid * 16 + j * 4096);
      gload_lds16(bx + (size_t)j * 32 * (D_ * 2), (char*)Bs + tid * 16 + j * 4096);
    }
    __syncthreads();

#pragma unroll
    for (int kk = 0; kk < 2; kk++) {
      const int pc = (((kk << 2) + quad) ^ sw) << 3;  // physical chunk offset (elems)
      bf16x8 a[4], bb[4];
#pragma unroll
      for (int i = 0; i < 4; i++)
        a[i] = *(const bf16x8*)(As + (wm * 64 + 16 * i + col) * 64 + pc);
#pragma unroll
      for (int j = 0; j < 4; j++)
        bb[j] = *(const bf16x8*)(Bs + (wn * 64 + 16 * j + col) * 64 + pc);
#pragma unroll
      for (int i = 0; i < 4; i++)
#pragma unroll
        for (int j = 0; j < 4; j++) acc[i][j] = MFMA16(a[i], bb[j], acc[i][j]);
    }
  }

  // epilogue (R7 direct-store form). C/D layout: row = quad*4+r, col = lane&15
  const float scale = (z == 0) ? 0.18033688f : 1.0f;  // 0.125 * log2(e) for Q
#pragma unroll
  for (int j = 0; j < 4; j++) {
    const int n = n0 + wn * 64 + 16 * j + col;
    const float bval = (float)bias[n];
    const int h = n >> 6, w = n & 63;
#pragma unroll
    for (int i = 0; i < 4; i++) {
      const int m = m0 + wm * 64 + 16 * i + quad * 4;
      const int b = m >> 11, s = m & 2047;
      if (z < 2) {
        __bf16* outp = ((z == 0) ? Qo : Ko) + ((size_t)(b * H_ + h) * S_ + s) * W_ + w;
#pragma unroll
        for (int r = 0; r < 4; r++) outp[(size_t)r * W_] = (__bf16)((acc[i][j][r] + bval) * scale);
      } else {
        bf16x4 v;
#pragma unroll
        for (int r = 0; r < 4; r++) v[r] = (__bf16)(acc[i][j][r] + bval);
        *(bf16x4*)(Vto + ((size_t)(b * H_ + h) * W_ + w) * S_ + s) = v;
      }
    }
  }
}

// ---------------------------------------------------------------------------
// Kernel 5: flash attention. Final frozen version (R2/R7, verified 3x):
//   S^T formulation, XOR-swizzled K/V LDS, double-buffer + prefetch across
//   the single per-tile barrier, in-register P via cvt_pk+permlane (T12),
//   setprio around MFMA clusters (T5), XCD chunk swizzle (T1).
// ---------------------------------------------------------------------------
__global__ __launch_bounds__(256, 4) void attn(
    const __bf16* __restrict__ Q, const __bf16* __restrict__ K,
    const __bf16* __restrict__ Vt, const int* __restrict__ mask,
    float* __restrict__ out) {
  __shared__ __align__(16) __bf16 Kl[2][64 * 64];  // [buf][key][w], chunk-swizzled
  __shared__ __align__(16) __bf16 Vl[2][64 * 64];  // [buf][w][key], chunk-swizzled
  __shared__ int Mfl[32];                          // per-tile: 1 = mask all ones

  const int tid = threadIdx.x, lane = tid & 63, wid = tid >> 6;
  const int quad = lane >> 4, col = lane & 15;
  // XCD chunk swizzle: 1024 blocks = 8 XCDs x 128. XCD k gets bh in [8k,8k+8),
  // qx fastest -> one head's 512KB K/V hot in its L2 at a time.
  const int id = blockIdx.x + (blockIdx.y << 4);
  const int nid = (id & 7) * 128 + (id >> 3);
  const int bh = nid >> 4, b = bh >> 4, h = bh & 15;
  const int qbase = (nid & 15) * 128 + wid * 32;
  const int sw = col & 7;

  // prologue: per-tile all-ones flags (wave w handles tiles w, w+4, ...)
  for (int kt2 = wid; kt2 < 32; kt2 += 4) {
    const int m = mask[b * S_ + kt2 * 64 + lane];
    const unsigned long long bal = __ballot(m != 0);
    if (lane == 0) Mfl[kt2] = (~bal == 0ull) ? 1 : 0;
  }

  // Q B-fragments (lane n=col holds Q[q][k=quad*8+j], kk chunks): qf[qg][kk]
  bf16x8 qf[2][2];
#pragma unroll
  for (int qg = 0; qg < 2; qg++) {
    const __bf16* qp = Q + ((size_t)bh * S_ + qbase + qg * 16 + col) * W_ + quad * 8;
    qf[qg][0] = *(const bf16x8*)qp;
    qf[qg][1] = *(const bf16x8*)(qp + 32);
  }

  f32x4 oacc[2][4] = {};
  float lrow[2] = {0.f, 0.f};

  // staging lanes: flat f -> row r (128B), chunk c; fetch global chunk c^(r&7)
  const int f1 = tid * 16, r1 = f1 >> 7, c1 = (f1 >> 4) & 7;
  const int f2 = f1 + 4096, r2 = f2 >> 7, c2 = (f2 >> 4) & 7;
  const int s1 = (c1 ^ (r1 & 7)) << 4, s2 = (c2 ^ (r2 & 7)) << 4;

#define STAGE_KV(kts, bufidx)                                                     \
  do {                                                                            \
    const int k0s = (kts) * 64;                                                   \
    const char* kg = (const char*)(K + ((size_t)bh * S_ + k0s) * W_);             \
    gload_lds16(kg + (size_t)r1 * 128 + s1, (char*)Kl[bufidx] + f1);              \
    gload_lds16(kg + (size_t)r2 * 128 + s2, (char*)Kl[bufidx] + f2);              \
    const char* vg = (const char*)(Vt + (size_t)bh * W_ * S_ + k0s);              \
    gload_lds16(vg + (size_t)r1 * (S_ * 2) + s1, (char*)Vl[bufidx] + f1);         \
    gload_lds16(vg + (size_t)r2 * (S_ * 2) + s2, (char*)Vl[bufidx] + f2);         \
  } while (0)

  // prologue stage of tile 0 into buffer 0
  STAGE_KV(0, 0);

  for (int kt = 0; kt < S_ / 64; ++kt) {
    const int cur = kt & 1;
    // single per-tile barrier: auto vmcnt drain covers tile-kt loads (issued a
    // full compute phase ago) + makes buf[cur^1] safe to overwrite.
    __syncthreads();
    if (kt + 1 < S_ / 64) STAGE_KV(kt + 1, cur ^ 1);

    const int allone = __builtin_amdgcn_readfirstlane(Mfl[kt]);
    const __bf16* Klc = Kl[cur];
    const __bf16* Vlc = Vl[cur];

    // St = K.Q^T : A-frag = K rows (m=key=16mt+col), B-frag = qf
    f32x4 sacc[2][4] = {};
    __builtin_amdgcn_s_setprio(1);
#pragma unroll
    for (int mt = 0; mt < 4; mt++) {
      const __bf16* kr = Klc + (16 * mt + col) * 64;
      const bf16x8 ka0 = *(const bf16x8*)(kr + ((quad ^ sw) << 3));
      const bf16x8 ka1 = *(const bf16x8*)(kr + (((4 + quad) ^ sw) << 3));
#pragma unroll
      for (int qg = 0; qg < 2; qg++) {
        sacc[qg][mt] = MFMA16(ka0, qf[qg][0], sacc[qg][mt]);
        sacc[qg][mt] = MFMA16(ka1, qf[qg][1], sacc[qg][mt]);
      }
    }
    __builtin_amdgcn_s_setprio(0);

    // additive mask slow path (wave-uniform branch; never taken for all-ones)
    if (!allone) {
      const int k0 = kt * 64;
#pragma unroll
      for (int mt = 0; mt < 4; mt++)
#pragma unroll
        for (int r = 0; r < 4; r++) {
          const int m = mask[b * S_ + k0 + 16 * mt + 4 * quad + r];
          const float madd = -14426.95f * (1.0f - (float)m);  // -10000*log2e
          sacc[0][mt][r] += madd;
          sacc[1][mt][r] += madd;
        }
    }

    // softmax partial: p = exp2(s') via raw v_exp_f32; vector l-sum;
    // pack P rows to dwords in-register (keys 4q+{0,1} in pkA, {2,3} in pkB)
    unsigned pkA[2][4], pkB[2][4];
#pragma unroll
    for (int qg = 0; qg < 2; qg++) {
      f32x4 vsum = {0.f, 0.f, 0.f, 0.f};
#pragma unroll
      for (int mt = 0; mt < 4; mt++) {
#pragma unroll
        for (int r = 0; r < 4; r++) sacc[qg][mt][r] = EXP2(sacc[qg][mt][r]);
        vsum += sacc[qg][mt];
      }
      float sum = (vsum[0] + vsum[1]) + (vsum[2] + vsum[3]);
      sum += __shfl_xor(sum, 16, 64);
      sum += __shfl_xor(sum, 32, 64);
      lrow[qg] += sum;
#pragma unroll
      for (int mt = 0; mt < 4; mt++) {
        __asm__("v_cvt_pk_bf16_f32 %0, %1, %2"
                : "=v"(pkA[qg][mt]) : "v"(sacc[qg][mt][0]), "v"(sacc[qg][mt][1]));
        __asm__("v_cvt_pk_bf16_f32 %0, %1, %2"
                : "=v"(pkB[qg][mt]) : "v"(sacc[qg][mt][2]), "v"(sacc[qg][mt][3]));
      }
    }

    // O^T += V^T.P^T : A-frag = V^T rows (m=w=16mt+col); B-frag built in-reg
    // via permlane32_swap + permlane16_swap (col fixed, quad permuted).
    __builtin_amdgcn_s_setprio(1);
#pragma unroll
    for (int kk = 0; kk < 2; kk++) {
      bf16x8 pf[2];
#pragma unroll
      for (int qg = 0; qg < 2; qg++) {
        unsigned a0 = pkA[qg][2 * kk], a1 = pkA[qg][2 * kk + 1];
        unsigned b0 = pkB[qg][2 * kk], b1 = pkB[qg][2 * kk + 1];
        __asm__("v_permlane32_swap_b32 %0, %1" : "+v"(a0), "+v"(a1));
        __asm__("v_permlane16_swap_b32 %0, %1" : "+v"(a0), "+v"(a1));
        __asm__("v_permlane32_swap_b32 %0, %1" : "+v"(b0), "+v"(b1));
        __asm__("v_permlane16_swap_b32 %0, %1" : "+v"(b0), "+v"(b1));
        // a0 = keys 8q+{0,1}, b0 = {2,3}, a1 = {4,5}, b1 = {6,7}
        union { unsigned u[4]; bf16x8 v; } pk_;
        pk_.u[0] = a0; pk_.u[1] = b0; pk_.u[2] = a1; pk_.u[3] = b1;
        pf[qg] = pk_.v;
      }
      const int vsw = ((kk * 4 + quad) ^ sw) << 3;
#pragma unroll
      for (int mt = 0; mt < 4; mt++) {
        const bf16x8 va = *(const bf16x8*)(Vlc + (16 * mt + col) * 64 + vsw);
        oacc[0][mt] = MFMA16(va, pf[0], oacc[0][mt]);
        oacc[1][mt] = MFMA16(va, pf[1], oacc[1][mt]);
      }
    }
    __builtin_amdgcn_s_setprio(0);
  }
#undef STAGE_KV

  // epilogue: lane holds O^T[w=16mt+quad*4+r][q=qg*16+col] -> fp32 dwordx4
#pragma unroll
  for (int qg = 0; qg < 2; qg++) {
    const float inv = 1.0f / lrow[qg];
    const int s = qbase + qg * 16 + col;
#pragma unroll
    for (int mt = 0; mt < 4; mt++) {
      f32x4 o;
#pragma unroll
      for (int r = 0; r < 4; r++) o[r] = oacc[qg][mt][r] * inv;
      *(f32x4*)(out + ((size_t)b * S_ + s) * D_ + h * 64 + 16 * mt + quad * 4) = o;
    }
  }
}

// ---------------------------------------------------------------------------
extern "C" void kernel_launch(void* const* d_in, const int* in_sizes, int n_in,
                              void* d_out, int out_size, void* d_ws, size_t ws_size,
                              hipStream_t stream) {
  const float* x  = (const float*)d_in[0];
  const int* mask = (const int*)d_in[1];
  const float* Wq = (const float*)d_in[2];
  const float* bq = (const float*)d_in[3];
  const float* Wk = (const float*)d_in[4];
  const float* bk = (const float*)d_in[5];
  const float* Wv = (const float*)d_in[6];
  const float* bv = (const float*)d_in[7];
  float* out = (float*)d_out;

  // d_out first half doubles as x-bf16 scratch; overwritten by attn at the end.
  __bf16* xb = (__bf16*)d_out;

  // ws: Q 16MB | K 16MB | V^T 16MB | Tq/Tk/Tv 3x2MB | bias 6KB
  char* ws = (char*)d_ws;
  __bf16* Qw  = (__bf16*)(ws);
  __bf16* Kw  = (__bf16*)(ws + 16777216);
  __bf16* Vtw = (__bf16*)(ws + 2 * 16777216);
  __bf16* Tq  = (__bf16*)(ws + 3 * 16777216);
  __bf16* Tk  = Tq + 1024 * 1024;
  __bf16* Tv  = Tk + 1024 * 1024;
  __bf16* biasb = Tv + 1024 * 1024;

  convx<<<4096, 256, 0, stream>>>(x, xb);
  wtrans<<<dim3(16, 16, 3), 256, 0, stream>>>(Wq, Wk, Wv, Tq, Tk, Tv);
  convb<<<3, 256, 0, stream>>>(bq, bk, bv, biasb);
  qkv_gemm<<<dim3(8, 64, 3), 256, 0, stream>>>(xb, Tq, Tk, Tv, biasb, Qw, Kw, Vtw);
  attn<<<dim3(16, 64), 256, 0, stream>>>(Qw, Kw, Vtw, mask, out);
}

// Round 12
// 235.996 us; speedup vs baseline: 1.0652x; 1.0299x over previous
//
#include <hip/hip_runtime.h>

// Problem: B=4, S=2048, D=1024, H=16, W=64.
// Inputs fp32, output fp32; compute in bf16 MFMA.
#define B_ 4
#define S_ 2048
#define D_ 1024
#define H_ 16
#define W_ 64

typedef __attribute__((ext_vector_type(8))) __bf16 bf16x8;
typedef __attribute__((ext_vector_type(4))) __bf16 bf16x4;
typedef __attribute__((ext_vector_type(4))) float f32x4;

static __device__ __forceinline__ void gload_lds16(const void* g, void* l) {
  __builtin_amdgcn_global_load_lds((const __attribute__((address_space(1))) void*)g,
                                   (__attribute__((address_space(3))) void*)l,
                                   16, 0, 0);
}

#define MFMA16(a, b, c) __builtin_amdgcn_mfma_f32_16x16x32_bf16((a), (b), (c), 0, 0, 0)

// Raw v_exp_f32 (2^x). exp2f libcall carries non-fast-math range checks (R6 lesson).
#if __has_builtin(__builtin_amdgcn_exp2f)
#define EXP2(x) __builtin_amdgcn_exp2f(x)
#else
#define EXP2(x) __expf((x) * 0.6931472f)
#endif

// ---------------------------------------------------------------------------
// Kernel 1: convert x (fp32) -> bf16 scratch. 8 elems/thread.
// ---------------------------------------------------------------------------
__global__ __launch_bounds__(256) void convx(const float* __restrict__ x,
                                             __bf16* __restrict__ xb) {
  const size_t i = ((size_t)blockIdx.x * 256 + threadIdx.x) * 8;
  const f32x4 v0 = *(const f32x4*)(x + i);
  const f32x4 v1 = *(const f32x4*)(x + i + 4);
  bf16x8 v;
#pragma unroll
  for (int k = 0; k < 4; k++) { v[k] = (__bf16)v0[k]; v[4 + k] = (__bf16)v1[k]; }
  *(bf16x8*)(xb + i) = v;
}

// ---------------------------------------------------------------------------
// Kernel 2: weight transpose+convert W[k][n] (fp32) -> T[n][k] bf16
// ---------------------------------------------------------------------------
__global__ __launch_bounds__(256) void wtrans(
    const float* __restrict__ Wq, const float* __restrict__ Wk, const float* __restrict__ Wv,
    __bf16* __restrict__ Tq, __bf16* __restrict__ Tk, __bf16* __restrict__ Tv) {
  __shared__ __bf16 t[64][65];
  const int z = blockIdx.z;
  const float* W = (z == 0) ? Wq : (z == 1) ? Wk : Wv;
  __bf16* T = (z == 0) ? Tq : (z == 1) ? Tk : Tv;
  const int n0 = blockIdx.x * 64, k0 = blockIdx.y * 64;
  const int row = threadIdx.x >> 2, c0 = (threadIdx.x & 3) * 16;
#pragma unroll
  for (int i = 0; i < 16; i++)
    t[row][c0 + i] = (__bf16)W[(size_t)(k0 + row) * D_ + n0 + c0 + i];
  __syncthreads();
#pragma unroll
  for (int i = 0; i < 16; i++) T[(size_t)(n0 + row) * D_ + k0 + c0 + i] = t[c0 + i][row];
}

// ---------------------------------------------------------------------------
// Kernel 3: bias convert fp32 -> bf16 in ws (3 x 1024)
// ---------------------------------------------------------------------------
__global__ __launch_bounds__(256) void convb(
    const float* __restrict__ bq, const float* __restrict__ bk, const float* __restrict__ bv,
    __bf16* __restrict__ dst) {
  const int z = blockIdx.x;
  const float* src = (z == 0) ? bq : (z == 1) ? bk : bv;
  const int i = threadIdx.x * 4;
#pragma unroll
  for (int k = 0; k < 4; k++) dst[z * 1024 + i + k] = (__bf16)src[i + k];
}

// ---------------------------------------------------------------------------
// Kernel 4: fused QKV projection GEMM. BK=64, m97-structure K-loop. Bijective
//   XCD chunk swizzle (R1: proven, FETCH_SIZE way down). Byte-identical to R7.
//   Q scaled by 0.125*log2(e); Q,K written [B,H,S,64]; V written [B,H,64,S].
// ---------------------------------------------------------------------------
__global__ __launch_bounds__(256) void qkv_gemm(
    const __bf16* __restrict__ x,
    const __bf16* __restrict__ Tq, const __bf16* __restrict__ Tk, const __bf16* __restrict__ Tv,
    const __bf16* __restrict__ biasb,
    __bf16* __restrict__ Qo, __bf16* __restrict__ Ko, __bf16* __restrict__ Vto) {
  __shared__ __align__(16) __bf16 As[128 * 64];  // [row][k], 128B rows, chunk-swizzled
  __shared__ __align__(16) __bf16 Bs[128 * 64];
  const int tid = threadIdx.x, lane = tid & 63;
  const int wid = tid >> 6, wm = wid >> 1, wn = wid & 1;
  const int quad = lane >> 4, col = lane & 15;
  const int sw = col & 7;
  // XCD chunk swizzle: 1536 blocks = 8 XCDs x 192. XCD k gets contiguous nids
  // [192k,192k+192): 24 consecutive (m,z)-panels x all 8 n-blocks.
  const int id = blockIdx.x + (blockIdx.y << 3) + (blockIdx.z << 9);
  const int nid = (id & 7) * 192 + (id >> 3);
  const int n0 = (nid & 7) * 128, m0 = ((nid >> 3) & 63) * 128, z = nid >> 9;
  const __bf16* Wt = (z == 0) ? Tq : (z == 1) ? Tk : Tv;
  const __bf16* bias = biasb + z * 1024;

  f32x4 acc[4][4] = {};

  // staging: thread's 16B chunk c=tid&7 of row r=(tid>>3)+32j; source chunk
  // swizzled c^(r&7) -> constant per-thread offset soff.
  const int srow = tid >> 3;
  const int soff = (((tid & 7) ^ ((tid >> 3) & 7)) << 4);

  for (int kt = 0; kt < D_ / 64; ++kt) {
    const int k0 = kt * 64;
    __syncthreads();
    const char* ax = (const char*)x + (size_t)(m0 + srow) * (D_ * 2) + k0 * 2 + soff;
    const char* bx = (const char*)Wt + (size_t)(n0 + srow) * (D_ * 2) + k0 * 2 + soff;
#pragma unroll
    for (int j = 0; j < 4; j++) {
      gload_lds16(ax + (size_t)j * 32 * (D_ * 2), (char*)As + tid * 16 + j * 4096);
      gload_lds16(bx + (size_t)j * 32 * (D_ * 2), (char*)Bs + tid * 16 + j * 4096);
    }
    __syncthreads();

#pragma unroll
    for (int kk = 0; kk < 2; kk++) {
      const int pc = (((kk << 2) + quad) ^ sw) << 3;  // physical chunk offset (elems)
      bf16x8 a[4], bb[4];
#pragma unroll
      for (int i = 0; i < 4; i++)
        a[i] = *(const bf16x8*)(As + (wm * 64 + 16 * i + col) * 64 + pc);
#pragma unroll
      for (int j = 0; j < 4; j++)
        bb[j] = *(const bf16x8*)(Bs + (wn * 64 + 16 * j + col) * 64 + pc);
#pragma unroll
      for (int i = 0; i < 4; i++)
#pragma unroll
        for (int j = 0; j < 4; j++) acc[i][j] = MFMA16(a[i], bb[j], acc[i][j]);
    }
  }

  // epilogue (R7 direct-store form). C/D layout: row = quad*4+r, col = lane&15
  const float scale = (z == 0) ? 0.18033688f : 1.0f;  // 0.125 * log2(e) for Q
#pragma unroll
  for (int j = 0; j < 4; j++) {
    const int n = n0 + wn * 64 + 16 * j + col;
    const float bval = (float)bias[n];
    const int h = n >> 6, w = n & 63;
#pragma unroll
    for (int i = 0; i < 4; i++) {
      const int m = m0 + wm * 64 + 16 * i + quad * 4;
      const int b = m >> 11, s = m & 2047;
      if (z < 2) {
        __bf16* outp = ((z == 0) ? Qo : Ko) + ((size_t)(b * H_ + h) * S_ + s) * W_ + w;
#pragma unroll
        for (int r = 0; r < 4; r++) outp[(size_t)r * W_] = (__bf16)((acc[i][j][r] + bval) * scale);
      } else {
        bf16x4 v;
#pragma unroll
        for (int r = 0; r < 4; r++) v[r] = (__bf16)(acc[i][j][r] + bval);
        *(bf16x4*)(Vto + ((size_t)(b * H_ + h) * W_ + w) * S_ + s) = v;
      }
    }
  }
}

// ---------------------------------------------------------------------------
// Kernel 5: flash attention. R7 structure with ONE isolated micro (R12):
//   mask flags in a per-wave REGISTER (the exact R3/R4/R5 prologue, 3x
//   correctness-proven) instead of the Mfl LDS array. Removes the per-tile
//   ds_read + lgkm wait after each barrier (32x) and drops LDS to exactly
//   32768B. Everything else byte-identical to R7/R11.
// ---------------------------------------------------------------------------
__global__ __launch_bounds__(256, 4) void attn(
    const __bf16* __restrict__ Q, const __bf16* __restrict__ K,
    const __bf16* __restrict__ Vt, const int* __restrict__ mask,
    float* __restrict__ out) {
  __shared__ __align__(16) __bf16 Kl[2][64 * 64];  // [buf][key][w], chunk-swizzled
  __shared__ __align__(16) __bf16 Vl[2][64 * 64];  // [buf][w][key], chunk-swizzled

  const int tid = threadIdx.x, lane = tid & 63, wid = tid >> 6;
  const int quad = lane >> 4, col = lane & 15;
  // XCD chunk swizzle: 1024 blocks = 8 XCDs x 128. XCD k gets bh in [8k,8k+8),
  // qx fastest -> one head's 512KB K/V hot in its L2 at a time.
  const int id = blockIdx.x + (blockIdx.y << 4);
  const int nid = (id & 7) * 128 + (id >> 3);
  const int bh = nid >> 4, b = bh >> 4, h = bh & 15;
  const int qbase = (nid & 15) * 128 + wid * 32;
  const int sw = col & 7;

  // staging lanes: flat f -> row r (128B), chunk c; fetch global chunk c^(r&7)
  const int f1 = tid * 16, r1 = f1 >> 7, c1 = (f1 >> 4) & 7;
  const int f2 = f1 + 4096, r2 = f2 >> 7, c2 = (f2 >> 4) & 7;
  const int s1 = (c1 ^ (r1 & 7)) << 4, s2 = (c2 ^ (r2 & 7)) << 4;

#define STAGE_KV(kts, bufidx)                                                     \
  do {                                                                            \
    const int k0s = (kts) * 64;                                                   \
    const char* kg = (const char*)(K + ((size_t)bh * S_ + k0s) * W_);             \
    gload_lds16(kg + (size_t)r1 * 128 + s1, (char*)Kl[bufidx] + f1);              \
    gload_lds16(kg + (size_t)r2 * 128 + s2, (char*)Kl[bufidx] + f2);              \
    const char* vg = (const char*)(Vt + (size_t)bh * W_ * S_ + k0s);              \
    gload_lds16(vg + (size_t)r1 * (S_ * 2) + s1, (char*)Vl[bufidx] + f1);         \
    gload_lds16(vg + (size_t)r2 * (S_ * 2) + s2, (char*)Vl[bufidx] + f2);         \
  } while (0)

  // prologue stage of tile 0 into buffer 0
  STAGE_KV(0, 0);

  // per-wave mask flag register: bit t = 1 iff mask tile t is all-ones
  // (exact R3/R4/R5 prologue — 3x correctness-proven)
  unsigned mflags = 0;
  for (int t = 0; t < 32; t++) {
    const int m = mask[b * S_ + t * 64 + lane];
    const unsigned long long bal = __ballot(m != 0);
    mflags |= ((~bal == 0ull) ? 1u : 0u) << t;
  }
  const unsigned mflags_s = __builtin_amdgcn_readfirstlane(mflags);

  // Q B-fragments (lane n=col holds Q[q][k=quad*8+j], kk chunks): qf[qg][kk]
  bf16x8 qf[2][2];
#pragma unroll
  for (int qg = 0; qg < 2; qg++) {
    const __bf16* qp = Q + ((size_t)bh * S_ + qbase + qg * 16 + col) * W_ + quad * 8;
    qf[qg][0] = *(const bf16x8*)qp;
    qf[qg][1] = *(const bf16x8*)(qp + 32);
  }

  f32x4 oacc[2][4] = {};
  float lrow[2] = {0.f, 0.f};

  for (int kt = 0; kt < S_ / 64; ++kt) {
    const int cur = kt & 1;
    // single per-tile barrier: auto vmcnt drain covers tile-kt loads (issued a
    // full compute phase ago) + makes buf[cur^1] safe to overwrite.
    __syncthreads();
    if (kt + 1 < S_ / 64) STAGE_KV(kt + 1, cur ^ 1);

    const int allone = (mflags_s >> kt) & 1;
    const __bf16* Klc = Kl[cur];
    const __bf16* Vlc = Vl[cur];

    // St = K.Q^T : A-frag = K rows (m=key=16mt+col), B-frag = qf
    f32x4 sacc[2][4] = {};
    __builtin_amdgcn_s_setprio(1);
#pragma unroll
    for (int mt = 0; mt < 4; mt++) {
      const __bf16* kr = Klc + (16 * mt + col) * 64;
      const bf16x8 ka0 = *(const bf16x8*)(kr + ((quad ^ sw) << 3));
      const bf16x8 ka1 = *(const bf16x8*)(kr + (((4 + quad) ^ sw) << 3));
#pragma unroll
      for (int qg = 0; qg < 2; qg++) {
        sacc[qg][mt] = MFMA16(ka0, qf[qg][0], sacc[qg][mt]);
        sacc[qg][mt] = MFMA16(ka1, qf[qg][1], sacc[qg][mt]);
      }
    }
    __builtin_amdgcn_s_setprio(0);

    // additive mask slow path (wave-uniform branch; never taken for all-ones)
    if (!allone) {
      const int k0 = kt * 64;
#pragma unroll
      for (int mt = 0; mt < 4; mt++)
#pragma unroll
        for (int r = 0; r < 4; r++) {
          const int m = mask[b * S_ + k0 + 16 * mt + 4 * quad + r];
          const float madd = -14426.95f * (1.0f - (float)m);  // -10000*log2e
          sacc[0][mt][r] += madd;
          sacc[1][mt][r] += madd;
        }
    }

    // softmax partial: p = exp2(s') via raw v_exp_f32; vector l-sum;
    // pack P rows to dwords in-register (keys 4q+{0,1} in pkA, {2,3} in pkB)
    unsigned pkA[2][4], pkB[2][4];
#pragma unroll
    for (int qg = 0; qg < 2; qg++) {
      f32x4 vsum = {0.f, 0.f, 0.f, 0.f};
#pragma unroll
      for (int mt = 0; mt < 4; mt++) {
#pragma unroll
        for (int r = 0; r < 4; r++) sacc[qg][mt][r] = EXP2(sacc[qg][mt][r]);
        vsum += sacc[qg][mt];
      }
      float sum = (vsum[0] + vsum[1]) + (vsum[2] + vsum[3]);
      sum += __shfl_xor(sum, 16, 64);
      sum += __shfl_xor(sum, 32, 64);
      lrow[qg] += sum;
#pragma unroll
      for (int mt = 0; mt < 4; mt++) {
        __asm__("v_cvt_pk_bf16_f32 %0, %1, %2"
                : "=v"(pkA[qg][mt]) : "v"(sacc[qg][mt][0]), "v"(sacc[qg][mt][1]));
        __asm__("v_cvt_pk_bf16_f32 %0, %1, %2"
                : "=v"(pkB[qg][mt]) : "v"(sacc[qg][mt][2]), "v"(sacc[qg][mt][3]));
      }
    }

    // O^T += V^T.P^T : A-frag = V^T rows (m=w=16mt+col); B-frag built in-reg
    // via permlane32_swap + permlane16_swap (col fixed, quad permuted).
    __builtin_amdgcn_s_setprio(1);
#pragma unroll
    for (int kk = 0; kk < 2; kk++) {
      bf16x8 pf[2];
#pragma unroll
      for (int qg = 0; qg < 2; qg++) {
        unsigned a0 = pkA[qg][2 * kk], a1 = pkA[qg][2 * kk + 1];
        unsigned b0 = pkB[qg][2 * kk], b1 = pkB[qg][2 * kk + 1];
        __asm__("v_permlane32_swap_b32 %0, %1" : "+v"(a0), "+v"(a1));
        __asm__("v_permlane16_swap_b32 %0, %1" : "+v"(a0), "+v"(a1));
        __asm__("v_permlane32_swap_b32 %0, %1" : "+v"(b0), "+v"(b1));
        __asm__("v_permlane16_swap_b32 %0, %1" : "+v"(b0), "+v"(b1));
        // a0 = keys 8q+{0,1}, b0 = {2,3}, a1 = {4,5}, b1 = {6,7}
        union { unsigned u[4]; bf16x8 v; } pk_;
        pk_.u[0] = a0; pk_.u[1] = b0; pk_.u[2] = a1; pk_.u[3] = b1;
        pf[qg] = pk_.v;
      }
      const int vsw = ((kk * 4 + quad) ^ sw) << 3;
#pragma unroll
      for (int mt = 0; mt < 4; mt++) {
        const bf16x8 va = *(const bf16x8*)(Vlc + (16 * mt + col) * 64 + vsw);
        oacc[0][mt] = MFMA16(va, pf[0], oacc[0][mt]);
        oacc[1][mt] = MFMA16(va, pf[1], oacc[1][mt]);
      }
    }
    __builtin_amdgcn_s_setprio(0);
  }
#undef STAGE_KV

  // epilogue: lane holds O^T[w=16mt+quad*4+r][q=qg*16+col] -> fp32 dwordx4
#pragma unroll
  for (int qg = 0; qg < 2; qg++) {
    const float inv = 1.0f / lrow[qg];
    const int s = qbase + qg * 16 + col;
#pragma unroll
    for (int mt = 0; mt < 4; mt++) {
      f32x4 o;
#pragma unroll
      for (int r = 0; r < 4; r++) o[r] = oacc[qg][mt][r] * inv;
      *(f32x4*)(out + ((size_t)b * S_ + s) * D_ + h * 64 + 16 * mt + quad * 4) = o;
    }
  }
}

// ---------------------------------------------------------------------------
extern "C" void kernel_launch(void* const* d_in, const int* in_sizes, int n_in,
                              void* d_out, int out_size, void* d_ws, size_t ws_size,
                              hipStream_t stream) {
  const float* x  = (const float*)d_in[0];
  const int* mask = (const int*)d_in[1];
  const float* Wq = (const float*)d_in[2];
  const float* bq = (const float*)d_in[3];
  const float* Wk = (const float*)d_in[4];
  const float* bk = (const float*)d_in[5];
  const float* Wv = (const float*)d_in[6];
  const float* bv = (const float*)d_in[7];
  float* out = (float*)d_out;

  // d_out first half doubles as x-bf16 scratch; overwritten by attn at the end.
  __bf16* xb = (__bf16*)d_out;

  // ws: Q 16MB | K 16MB | V^T 16MB | Tq/Tk/Tv 3x2MB | bias 6KB
  char* ws = (char*)d_ws;
  __bf16* Qw  = (__bf16*)(ws);
  __bf16* Kw  = (__bf16*)(ws + 16777216);
  __bf16* Vtw = (__bf16*)(ws + 2 * 16777216);
  __bf16* Tq  = (__bf16*)(ws + 3 * 16777216);
  __bf16* Tk  = Tq + 1024 * 1024;
  __bf16* Tv  = Tk + 1024 * 1024;
  __bf16* biasb = Tv + 1024 * 1024;

  convx<<<4096, 256, 0, stream>>>(x, xb);
  wtrans<<<dim3(16, 16, 3), 256, 0, stream>>>(Wq, Wk, Wv, Tq, Tk, Tv);
  convb<<<3, 256, 0, stream>>>(bq, bk, bv, biasb);
  qkv_gemm<<<dim3(8, 64, 3), 256, 0, stream>>>(xb, Tq, Tk, Tv, biasb, Qw, Kw, Vtw);
  attn<<<dim3(16, 64), 256, 0, stream>>>(Qw, Kw, Vtw, mask, out);
}